// Round 9
// baseline (133.906 us; speedup 1.0000x reference)
//
#include <hip/hip_runtime.h>
#include <math.h>

// BlockNet: 4× (unfold-linear ⊕ conv ⊕ sigmoid-gate blend, ReLU) + FC(32->4).
// Round 9: block1_fused4 — (a) w_uc reads moved to the VMEM pipe via
// divergent addressing (wkr NOT readfirstlane'd -> global_load_dwordx4
// broadcast, vmcnt domain, no lgkmcnt interference with ds_read), only
// wp/wl stay in LDS (1.5 KB); (b) x tile double-buffered (2x16 KB), one
// barrier per phase, next-phase loads issued before compute (T14 split).
// CFG: (cin,cout,k,s,oh) = (3,4,5,3,20),(4,6,3,2,9),(6,16,3,2,4),(16,32,3,2,1)

__device__ __forceinline__ float sigmoidf_(float x) {
    return 1.0f / (1.0f + expf(-x));
}

// ---------------------------------------------------------------------------
// block1 fused v4: grid (B/64, 20), 256 threads.
// WG: batches [b0,b0+64), output row i. wave wkr owns j in [wkr*5, wkr*5+5).
// lane = batch. 15 phases p=(c,a), dbuf: load p+1 -> compute p -> write p+1.
__global__ __launch_bounds__(256)
void block1_fused4(const float* __restrict__ x,     // (B,3,64,64)
                   const float* __restrict__ w_uc,  // (400*75, 4)
                   const float* __restrict__ b_uc,  // (4*400)
                   const float* __restrict__ w_pc,  // (4,75)
                   const float* __restrict__ b_pc,  // (4)
                   const float* __restrict__ w_wl,  // (75)
                   const float* __restrict__ b_wl,  // (1)
                   float* __restrict__ y1t,         // (1600, B)
                   int B)
{
    __shared__ __align__(16) float xs[2][4096];     // [buf][col][swz(b)]
    __shared__ __align__(16) float wp_s[300];       // [n][o]
    __shared__ float wl_s[75];

    const int tid  = threadIdx.x;
    const int lane = tid & 63;
    const int wkr  = tid >> 6;          // divergent on purpose (VMEM weights)
    const int b0   = blockIdx.x * 64;
    const int i    = blockIdx.y;        // output row

    // ---- stage small weight tables (strided loops; no dead predicates) ----
    for (int idx = tid; idx < 300; idx += 256)
        wp_s[idx] = w_pc[(idx & 3) * 75 + (idx >> 2)];   // [n][o] <- (o,n)
    for (int idx = tid; idx < 75; idx += 256)
        wl_s[idx] = w_wl[idx];

    // ---- stage phase 0 (c=0,a=0) into xs[0] ----
    #pragma unroll
    for (int q4 = 0; q4 < 4; ++q4) {
        const int idx = q4 * 256 + tid;
        const int b   = idx >> 4;           // 0..63
        const int cg  = idx & 15;           // 0..15
        const float4 v = *reinterpret_cast<const float4*>(
            &x[(size_t)(b0 + b) * 12288 + (size_t)(i * 3) * 64 + cg * 4]);
        const int col = cg * 4;
        const int sb  = b ^ ((cg & 7) << 2);
        xs[0][(col + 0) * 64 + sb] = v.x;
        xs[0][(col + 1) * 64 + sb] = v.y;
        xs[0][(col + 2) * 64 + sb] = v.z;
        xs[0][(col + 3) * 64 + sb] = v.w;
    }
    __syncthreads();

    float au[4][5], ap[4][5], ag[5];
    #pragma unroll
    for (int o = 0; o < 4; ++o)
        #pragma unroll
        for (int jj = 0; jj < 5; ++jj) { au[o][jj] = 0.f; ap[o][jj] = 0.f; }
    #pragma unroll
    for (int jj = 0; jj < 5; ++jj) ag[jj] = 0.f;

    // per-wave w_uc slice base: j0 = wkr*5 -> float offset (i*20+j0)*300
    const float* wu_base = w_uc + (size_t)(i * 20 + wkr * 5) * 300;

    #pragma unroll 1
    for (int p = 0; p < 15; ++p) {
        // ---- A) issue next phase's global x loads (drain under compute) ---
        float4 nv0, nv1, nv2, nv3;
        if (p < 14) {
            const int pn = p + 1;
            const int cn = pn / 5;
            const int an = pn - cn * 5;
            const size_t roff = (size_t)cn * 4096 + (size_t)(i * 3 + an) * 64;
            {   const int idx = tid;        const int b = idx >> 4, cg = idx & 15;
                nv0 = *reinterpret_cast<const float4*>(&x[(size_t)(b0 + b) * 12288 + roff + cg * 4]); }
            {   const int idx = 256 + tid;  const int b = idx >> 4, cg = idx & 15;
                nv1 = *reinterpret_cast<const float4*>(&x[(size_t)(b0 + b) * 12288 + roff + cg * 4]); }
            {   const int idx = 512 + tid;  const int b = idx >> 4, cg = idx & 15;
                nv2 = *reinterpret_cast<const float4*>(&x[(size_t)(b0 + b) * 12288 + roff + cg * 4]); }
            {   const int idx = 768 + tid;  const int b = idx >> 4, cg = idx & 15;
                nv3 = *reinterpret_cast<const float4*>(&x[(size_t)(b0 + b) * 12288 + roff + cg * 4]); }
        }

        // ---- B) compute phase p from xs[p&1] ----
        const float* xbuf = xs[p & 1];
        float xv[17];
        #pragma unroll
        for (int t = 0; t < 17; ++t) {
            const int col = wkr * 15 + t;
            xv[t] = xbuf[col * 64 + (lane ^ (((col >> 2) & 7) << 2))];
        }
        const int n0 = p * 5;               // = c*25 + a*5
        #pragma unroll
        for (int b2 = 0; b2 < 5; ++b2) {
            const float  wlv = wl_s[n0 + b2];
            const float4 wp4 = *reinterpret_cast<const float4*>(&wp_s[(n0 + b2) * 4]);
            #pragma unroll
            for (int jj = 0; jj < 5; ++jj) {
                const float v = xv[3 * jj + b2];
                const float4 w4 = *reinterpret_cast<const float4*>(
                    &wu_base[(jj * 75 + n0 + b2) * 4]);   // VMEM broadcast
                ag[jj]    += v * wlv;
                au[0][jj] += v * w4.x;  au[1][jj] += v * w4.y;
                au[2][jj] += v * w4.z;  au[3][jj] += v * w4.w;
                ap[0][jj] += v * wp4.x; ap[1][jj] += v * wp4.y;
                ap[2][jj] += v * wp4.z; ap[3][jj] += v * wp4.w;
            }
        }

        // ---- C) write staged row into xs[(p+1)&1] ----
        if (p < 14) {
            float* dstb = xs[(p + 1) & 1];
            {   const int idx = tid;        const int b = idx >> 4, cg = idx & 15;
                const int col = cg * 4, sb = b ^ ((cg & 7) << 2);
                dstb[(col+0)*64+sb] = nv0.x; dstb[(col+1)*64+sb] = nv0.y;
                dstb[(col+2)*64+sb] = nv0.z; dstb[(col+3)*64+sb] = nv0.w; }
            {   const int idx = 256 + tid;  const int b = idx >> 4, cg = idx & 15;
                const int col = cg * 4, sb = b ^ ((cg & 7) << 2);
                dstb[(col+0)*64+sb] = nv1.x; dstb[(col+1)*64+sb] = nv1.y;
                dstb[(col+2)*64+sb] = nv1.z; dstb[(col+3)*64+sb] = nv1.w; }
            {   const int idx = 512 + tid;  const int b = idx >> 4, cg = idx & 15;
                const int col = cg * 4, sb = b ^ ((cg & 7) << 2);
                dstb[(col+0)*64+sb] = nv2.x; dstb[(col+1)*64+sb] = nv2.y;
                dstb[(col+2)*64+sb] = nv2.z; dstb[(col+3)*64+sb] = nv2.w; }
            {   const int idx = 768 + tid;  const int b = idx >> 4, cg = idx & 15;
                const int col = cg * 4, sb = b ^ ((cg & 7) << 2);
                dstb[(col+0)*64+sb] = nv3.x; dstb[(col+1)*64+sb] = nv3.y;
                dstb[(col+2)*64+sb] = nv3.z; dstb[(col+3)*64+sb] = nv3.w; }
        }
        __syncthreads();
    }

    // ---- epilogue: gate blend + ReLU, batch-last coalesced stores ----
    const float bwl = b_wl[0];
    #pragma unroll
    for (int jj = 0; jj < 5; ++jj) {
        const int l = i * 20 + wkr * 5 + jj;
        const float g = sigmoidf_(ag[jj] + bwl);
        #pragma unroll
        for (int o = 0; o < 4; ++o) {
            const float x1 = au[o][jj] + b_uc[o * 400 + l];
            const float x2 = ap[o][jj] + b_pc[o];
            y1t[(size_t)(o * 400 + l) * B + b0 + lane] =
                fmaxf(x1 * g + x2 * (1.f - g), 0.f);
        }
    }
}

// ------------- batch-last block kernel: wave owns one location l ----------
template<int CIN, int COUT, int K, int S, int OH, int IH, int VB>
__global__ __launch_bounds__(256)
void blockT_kernel(const float* __restrict__ in_t,
                   const float* __restrict__ w_uc,  // (L*LN, COUT)
                   const float* __restrict__ b_uc,  // (COUT*L)
                   const float* __restrict__ w_pc,  // (COUT, LN)
                   const float* __restrict__ b_pc,  // (COUT)
                   const float* __restrict__ w_wl,  // (LN)
                   const float* __restrict__ b_wl,  // (1)
                   float* __restrict__ out_t,
                   int B)
{
    constexpr int LN = CIN * K * K;
    constexpr int L  = OH * OH;
    const int wv   = threadIdx.x >> 6;
    const int lane = threadIdx.x & 63;
    const int l    = __builtin_amdgcn_readfirstlane(blockIdx.y * 4 + wv);
    if (l >= L) return;
    const int i = l / OH, j = l % OH;
    const int b = blockIdx.x * (64 * VB) + lane * VB;

    float au[COUT][VB], ap[COUT][VB], ag[VB];
    #pragma unroll
    for (int o = 0; o < COUT; ++o)
        #pragma unroll
        for (int q = 0; q < VB; ++q) { au[o][q] = 0.f; ap[o][q] = 0.f; }
    #pragma unroll
    for (int q = 0; q < VB; ++q) ag[q] = 0.f;

    const float* wu = w_uc + (size_t)l * LN * COUT;

    #pragma unroll
    for (int c = 0; c < CIN; ++c)
    #pragma unroll
    for (int a = 0; a < K; ++a)
    #pragma unroll
    for (int b2 = 0; b2 < K; ++b2) {
        const int n = c * K * K + a * K + b2;
        const int p = c * IH * IH + (i * S + a) * IH + (j * S + b2);
        float v[VB];
        const float* src = in_t + (size_t)p * B + b;
        if constexpr (VB == 4) {
            const float4 t = *reinterpret_cast<const float4*>(src);
            v[0] = t.x; v[1] = t.y; v[2] = t.z; v[3] = t.w;
        } else if constexpr (VB == 2) {
            const float2 t = *reinterpret_cast<const float2*>(src);
            v[0] = t.x; v[1] = t.y;
        } else {
            v[0] = src[0];
        }
        const float wl = w_wl[n];
        #pragma unroll
        for (int q = 0; q < VB; ++q) ag[q] += v[q] * wl;
        #pragma unroll
        for (int o = 0; o < COUT; ++o) {
            const float wuv = wu[n * COUT + o];
            const float wpv = w_pc[o * LN + n];
            #pragma unroll
            for (int q = 0; q < VB; ++q) {
                au[o][q] += v[q] * wuv;
                ap[o][q] += v[q] * wpv;
            }
        }
    }

    const float bwl = b_wl[0];
    float g[VB];
    #pragma unroll
    for (int q = 0; q < VB; ++q) g[q] = sigmoidf_(ag[q] + bwl);

    #pragma unroll
    for (int o = 0; o < COUT; ++o) {
        const float buc = b_uc[o * L + l];
        const float bpc = b_pc[o];
        float y[VB];
        #pragma unroll
        for (int q = 0; q < VB; ++q) {
            const float x1 = au[o][q] + buc;
            const float x2 = ap[o][q] + bpc;
            y[q] = fmaxf(x1 * g[q] + x2 * (1.f - g[q]), 0.f);
        }
        float* dst = out_t + (size_t)(o * L + l) * B + b;
        if constexpr (VB == 4) {
            float4 t; t.x = y[0]; t.y = y[1]; t.z = y[2]; t.w = y[3];
            *reinterpret_cast<float4*>(dst) = t;
        } else if constexpr (VB == 2) {
            float2 t; t.x = y[0]; t.y = y[1];
            *reinterpret_cast<float2*>(dst) = t;
        } else {
            dst[0] = y[0];
        }
    }
}

// ---------- block4 (cin=16,k=3,s=2,oh=1,cout=32) + FC(32->4), batch-last ---
__global__ __launch_bounds__(256)
void block4T_fc(const float* __restrict__ in_t,  // (256, B)
                const float* __restrict__ w_uc,  // (144,32)
                const float* __restrict__ b_uc,  // (32)
                const float* __restrict__ w_pc,  // (32,144)
                const float* __restrict__ b_pc,  // (32)
                const float* __restrict__ w_wl,  // (144)
                const float* __restrict__ b_wl,  // (1)
                const float* __restrict__ fc_w,  // (32,4)
                const float* __restrict__ fc_b,  // (4)
                float* __restrict__ out,         // (B,4)
                int B)
{
    __shared__ __align__(16) float wu_s[144 * 36];
    __shared__ __align__(16) float wp_s[144 * 36];
    __shared__ float wl_s[144];
    __shared__ float buc_s[32], bpc_s[32], fcw_s[128], fcb_s[4];
    __shared__ float red[4][64][5];

    const int tid  = threadIdx.x;
    const int wv   = tid >> 6;
    const int lane = tid & 63;
    const int o0   = __builtin_amdgcn_readfirstlane(wv * 8);
    const int b    = blockIdx.x * 64 + lane;

    for (int idx = tid; idx < 144 * 32; idx += 256) {
        wu_s[(idx >> 5) * 36 + (idx & 31)] = w_uc[idx];
        const int o = idx / 144, n = idx - o * 144;
        wp_s[n * 36 + o] = w_pc[idx];
    }
    if (tid < 144) wl_s[tid] = w_wl[tid];
    if (tid < 32)  { buc_s[tid] = b_uc[tid]; bpc_s[tid] = b_pc[tid]; }
    if (tid >= 64 && tid < 192) fcw_s[tid - 64] = fc_w[tid - 64];
    if (tid >= 192 && tid < 196) fcb_s[tid - 192] = fc_b[tid - 192];
    __syncthreads();

    float au[8], apc[8], ag = 0.f;
    #pragma unroll
    for (int oo = 0; oo < 8; ++oo) { au[oo] = 0.f; apc[oo] = 0.f; }

    #pragma unroll
    for (int c = 0; c < 16; ++c) {
        float v[9];
        #pragma unroll
        for (int a = 0; a < 3; ++a)
        #pragma unroll
        for (int b2 = 0; b2 < 3; ++b2)
            v[a * 3 + b2] = in_t[(size_t)(c * 16 + a * 4 + b2) * B + b];

        #pragma unroll
        for (int t = 0; t < 9; ++t) {
            const int n = c * 9 + t;
            ag += v[t] * wl_s[n];
            const float4 wuA = *reinterpret_cast<const float4*>(&wu_s[n * 36 + o0]);
            const float4 wuB = *reinterpret_cast<const float4*>(&wu_s[n * 36 + o0 + 4]);
            const float4 wpA = *reinterpret_cast<const float4*>(&wp_s[n * 36 + o0]);
            const float4 wpB = *reinterpret_cast<const float4*>(&wp_s[n * 36 + o0 + 4]);
            au[0] += v[t] * wuA.x;  au[1] += v[t] * wuA.y;
            au[2] += v[t] * wuA.z;  au[3] += v[t] * wuA.w;
            au[4] += v[t] * wuB.x;  au[5] += v[t] * wuB.y;
            au[6] += v[t] * wuB.z;  au[7] += v[t] * wuB.w;
            apc[0] += v[t] * wpA.x; apc[1] += v[t] * wpA.y;
            apc[2] += v[t] * wpA.z; apc[3] += v[t] * wpA.w;
            apc[4] += v[t] * wpB.x; apc[5] += v[t] * wpB.y;
            apc[6] += v[t] * wpB.z; apc[7] += v[t] * wpB.w;
        }
    }

    const float g = sigmoidf_(ag + b_wl[0]);
    float pf[4] = {0.f, 0.f, 0.f, 0.f};
    #pragma unroll
    for (int oo = 0; oo < 8; ++oo) {
        const int o = o0 + oo;
        const float h = fmaxf((au[oo] + buc_s[o]) * g +
                              (apc[oo] + bpc_s[o]) * (1.f - g), 0.f);
        #pragma unroll
        for (int f = 0; f < 4; ++f) pf[f] += h * fcw_s[o * 4 + f];
    }
    #pragma unroll
    for (int f = 0; f < 4; ++f) red[wv][lane][f] = pf[f];
    __syncthreads();
    if (wv == 0) {
        float4 s;
        s.x = fcb_s[0] + red[0][lane][0] + red[1][lane][0] + red[2][lane][0] + red[3][lane][0];
        s.y = fcb_s[1] + red[0][lane][1] + red[1][lane][1] + red[2][lane][1] + red[3][lane][1];
        s.z = fcb_s[2] + red[0][lane][2] + red[1][lane][2] + red[2][lane][2] + red[3][lane][2];
        s.w = fcb_s[3] + red[0][lane][3] + red[1][lane][3] + red[2][lane][3] + red[3][lane][3];
        *reinterpret_cast<float4*>(out + (size_t)b * 4) = s;
    }
}

// ======================= fallback path (round-1, NCHW) ====================
template<int CIN, int COUT, int K, int S, int OH, int IH, int BPB>
__global__ __launch_bounds__(256)
void block_kernel(const float* __restrict__ in,
                  const float* __restrict__ w_uc,
                  const float* __restrict__ b_uc,
                  const float* __restrict__ w_pc,
                  const float* __restrict__ b_pc,
                  const float* __restrict__ w_wl,
                  const float* __restrict__ b_wl,
                  float* __restrict__ out,
                  int B)
{
    constexpr int LN   = CIN * K * K;
    constexpr int L    = OH * OH;
    constexpr int TILE = CIN * IH * IH;
    __shared__ __align__(16) float lds[BPB * TILE];

    const int b0 = blockIdx.x * BPB;
    const int nb = (B - b0 < BPB) ? (B - b0) : BPB;
    const int tot = nb * TILE;
    const float* src = in + (size_t)b0 * TILE;
    if ((tot & 3) == 0) {
        const float4* s4 = reinterpret_cast<const float4*>(src);
        float4* d4 = reinterpret_cast<float4*>(lds);
        for (int idx = threadIdx.x; idx < (tot >> 2); idx += blockDim.x) d4[idx] = s4[idx];
    } else {
        for (int idx = threadIdx.x; idx < tot; idx += blockDim.x) lds[idx] = src[idx];
    }
    __syncthreads();

    const float bwl = b_wl[0];
    for (int t = threadIdx.x; t < nb * L; t += blockDim.x) {
        const int bb = t / L;
        const int l  = t % L;
        const int i  = l / OH, j = l % OH;
        const float* tile = lds + bb * TILE;

        float acc_uc[COUT], acc_pc[COUT];
        #pragma unroll
        for (int o = 0; o < COUT; ++o) { acc_uc[o] = 0.f; acc_pc[o] = 0.f; }
        float acc_g = 0.f;

        const float* wu = w_uc + (size_t)l * LN * COUT;
        #pragma unroll
        for (int c = 0; c < CIN; ++c)
        #pragma unroll
        for (int a = 0; a < K; ++a)
        #pragma unroll
        for (int b2 = 0; b2 < K; ++b2) {
            const int n = c * K * K + a * K + b2;
            const float v = tile[c * IH * IH + (i * S + a) * IH + (j * S + b2)];
            acc_g += v * w_wl[n];
            #pragma unroll
            for (int o = 0; o < COUT; ++o) acc_uc[o] += v * wu[n * COUT + o];
            #pragma unroll
            for (int o = 0; o < COUT; ++o) acc_pc[o] += v * w_pc[o * LN + n];
        }

        const float g = sigmoidf_(acc_g + bwl);
        const size_t ob = (size_t)(b0 + bb) * COUT * L;
        #pragma unroll
        for (int o = 0; o < COUT; ++o) {
            const float x1 = acc_uc[o] + b_uc[o * L + l];
            const float x2 = acc_pc[o] + b_pc[o];
            out[ob + o * L + l] = fmaxf(x1 * g + x2 * (1.f - g), 0.f);
        }
    }
}

__global__ __launch_bounds__(256)
void block4_fc_kernel(const float* __restrict__ in,
                      const float* __restrict__ w_uc,
                      const float* __restrict__ b_uc,
                      const float* __restrict__ w_pc,
                      const float* __restrict__ b_pc,
                      const float* __restrict__ w_wl,
                      const float* __restrict__ b_wl,
                      const float* __restrict__ fc_w,
                      const float* __restrict__ fc_b,
                      float* __restrict__ out,
                      int B)
{
    __shared__ float hbuf[8][32];
    const int bl = threadIdx.x >> 5;
    const int o  = threadIdx.x & 31;
    const int b  = blockIdx.x * 8 + bl;

    if (b < B) {
        const float* xb = in + (size_t)b * 256;
        float acc_uc = 0.f, acc_pc = 0.f, acc_g = 0.f;
        #pragma unroll
        for (int c = 0; c < 16; ++c)
        #pragma unroll
        for (int a = 0; a < 3; ++a)
        #pragma unroll
        for (int b2 = 0; b2 < 3; ++b2) {
            const int n = c * 9 + a * 3 + b2;
            const float v = xb[c * 16 + a * 4 + b2];
            acc_uc += v * w_uc[n * 32 + o];
            acc_pc += v * w_pc[o * 144 + n];
            acc_g  += v * w_wl[n];
        }
        const float g  = sigmoidf_(acc_g + b_wl[0]);
        hbuf[bl][o] = fmaxf((acc_uc + b_uc[o]) * g + (acc_pc + b_pc[o]) * (1.f - g), 0.f);
    }
    __syncthreads();

    if (threadIdx.x < 32) {
        const int bl2 = threadIdx.x >> 2;
        const int f   = threadIdx.x & 3;
        const int bb  = blockIdx.x * 8 + bl2;
        if (bb < B) {
            float s = fc_b[f];
            #pragma unroll
            for (int oo = 0; oo < 32; ++oo) s += hbuf[bl2][oo] * fc_w[oo * 4 + f];
            out[(size_t)bb * 4 + f] = s;
        }
    }
}

// ==========================================================================
extern "C" void kernel_launch(void* const* d_in, const int* in_sizes, int n_in,
                              void* d_out, int out_size, void* d_ws, size_t ws_size,
                              hipStream_t stream) {
    const float* x    = (const float*)d_in[0];
    const float* wuc1 = (const float*)d_in[1];
    const float* buc1 = (const float*)d_in[2];
    const float* wpc1 = (const float*)d_in[3];
    const float* bpc1 = (const float*)d_in[4];
    const float* wwl1 = (const float*)d_in[5];
    const float* bwl1 = (const float*)d_in[6];
    const float* wuc2 = (const float*)d_in[7];
    const float* buc2 = (const float*)d_in[8];
    const float* wpc2 = (const float*)d_in[9];
    const float* bpc2 = (const float*)d_in[10];
    const float* wwl2 = (const float*)d_in[11];
    const float* bwl2 = (const float*)d_in[12];
    const float* wuc3 = (const float*)d_in[13];
    const float* buc3 = (const float*)d_in[14];
    const float* wpc3 = (const float*)d_in[15];
    const float* bpc3 = (const float*)d_in[16];
    const float* wwl3 = (const float*)d_in[17];
    const float* bwl3 = (const float*)d_in[18];
    const float* wuc4 = (const float*)d_in[19];
    const float* buc4 = (const float*)d_in[20];
    const float* wpc4 = (const float*)d_in[21];
    const float* bpc4 = (const float*)d_in[22];
    const float* wwl4 = (const float*)d_in[23];
    const float* bwl4 = (const float*)d_in[24];
    const float* fcw  = (const float*)d_in[25];
    const float* fcb  = (const float*)d_in[26];

    const int B = in_sizes[0] / (3 * 64 * 64);   // 2048
    float* ws = (float*)d_ws;
    const size_t need = sizeof(float) * (size_t)(1600 + 486 + 256) * B;

    if (ws_size >= need && (B % 256) == 0) {
        // ---------------- batch-last fast path (fused block1 v4) ----------
        float* y1 = ws;                             // (1600, B)
        float* y2 = y1 + (size_t)1600 * B;          // (486, B)
        float* y3 = y2 + (size_t)486 * B;           // (256, B)

        block1_fused4<<<dim3(B / 64, 20), 256, 0, stream>>>(
            x, wuc1, buc1, wpc1, bpc1, wwl1, bwl1, y1, B);
        blockT_kernel<4, 6, 3, 2, 9, 20, 2>
            <<<dim3(B / 128, 21), 256, 0, stream>>>(y1, wuc2, buc2, wpc2, bpc2, wwl2, bwl2, y2, B);
        blockT_kernel<6, 16, 3, 2, 4, 9, 1>
            <<<dim3(B / 64, 4), 256, 0, stream>>>(y2, wuc3, buc3, wpc3, bpc3, wwl3, bwl3, y3, B);
        block4T_fc<<<B / 64, 256, 0, stream>>>(y3, wuc4, buc4, wpc4, bpc4, wwl4, bwl4,
                                               fcw, fcb, (float*)d_out, B);
    } else {
        // ---------------- fallback (round-1) ----------------
        float* y1 = ws;
        float* y2 = y1 + (size_t)B * 4 * 400;
        float* y3 = y2 + (size_t)B * 6 * 81;
        block_kernel<3, 4, 5, 3, 20, 64, 1>
            <<<B, 256, 0, stream>>>(x, wuc1, buc1, wpc1, bpc1, wwl1, bwl1, y1, B);
        block_kernel<4, 6, 3, 2, 9, 20, 4>
            <<<(B + 3) / 4, 256, 0, stream>>>(y1, wuc2, buc2, wpc2, bpc2, wwl2, bwl2, y2, B);
        block_kernel<6, 16, 3, 2, 4, 9, 16>
            <<<(B + 15) / 16, 256, 0, stream>>>(y2, wuc3, buc3, wpc3, bpc3, wwl3, bwl3, y3, B);
        block4_fc_kernel<<<(B + 7) / 8, 256, 0, stream>>>(
            y3, wuc4, buc4, wpc4, bpc4, wwl4, bwl4, fcw, fcb, (float*)d_out, B);
    }
}

// Round 10
// 114.179 us; speedup vs baseline: 1.1728x; 1.1728x over previous
//
#include <hip/hip_runtime.h>
#include <math.h>

// BlockNet: 4× (unfold-linear ⊕ conv ⊕ sigmoid-gate blend, ReLU) + FC(32->4).
// Round 10: block1_fused5 — v4's double-buffered phase pipeline, but weights
// restored to LDS (broadcast ds_reads; v4's per-phase VMEM weights exposed L2
// latency and regressed). w_uc staged per-phase (400 floats) into a 2x1.6 KB
// dbuf prefetched alongside x. LDS 36.8 KB -> all 2.5 WG/CU resident.
// CFG: (cin,cout,k,s,oh) = (3,4,5,3,20),(4,6,3,2,9),(6,16,3,2,4),(16,32,3,2,1)

__device__ __forceinline__ float sigmoidf_(float x) {
    return 1.0f / (1.0f + expf(-x));
}

// ---------------------------------------------------------------------------
// block1 fused v5: grid (B/64, 20), 256 threads.
// WG: batches [b0,b0+64), output row i. wave wkr owns j in [wkr*5, wkr*5+5).
// lane = batch. 15 phases p=(c,a): prefetch x[p+1] (4 f4) + wu[p+1] (100 f4,
// threads<100), compute p from LDS, write staged data, one barrier.
__global__ __launch_bounds__(256)
void block1_fused5(const float* __restrict__ x,     // (B,3,64,64)
                   const float* __restrict__ w_uc,  // (400*75, 4)
                   const float* __restrict__ b_uc,  // (4*400)
                   const float* __restrict__ w_pc,  // (4,75)
                   const float* __restrict__ b_pc,  // (4)
                   const float* __restrict__ w_wl,  // (75)
                   const float* __restrict__ b_wl,  // (1)
                   float* __restrict__ y1t,         // (1600, B)
                   int B)
{
    __shared__ __align__(16) float xs[2][4096];     // [buf][col][swz(b)]
    __shared__ __align__(16) float wu2[2][400];     // [buf][j][tap][o]
    __shared__ __align__(16) float wp_s[300];       // [n][o]
    __shared__ float wl_s[75];

    const int tid  = threadIdx.x;
    const int lane = tid & 63;
    const int wkr  = __builtin_amdgcn_readfirstlane(tid >> 6);  // 0..3
    const int b0   = blockIdx.x * 64;
    const int i    = blockIdx.y;                    // output row

    // w_uc in float4 units: wuc4[(i*20+j)*75 + n] = 4 couts of tap n at loc (i,j)
    const float4* wuc4 = reinterpret_cast<const float4*>(w_uc) + (size_t)i * 20 * 75;
    const int jw  = tid / 5;            // staging row 0..51 (only <20 used via tid<100)
    const int tap = tid - jw * 5;

    // ---- stage small weight tables (strided; no dead predicates) ----
    for (int idx = tid; idx < 300; idx += 256)
        wp_s[idx] = w_pc[(idx & 3) * 75 + (idx >> 2)];   // [n][o] <- (o,n)
    for (int idx = tid; idx < 75; idx += 256)
        wl_s[idx] = w_wl[idx];

    // ---- stage phase 0: x row (c=0,a=0) into xs[0], wu taps 0..4 into wu2[0]
    #pragma unroll
    for (int q4 = 0; q4 < 4; ++q4) {
        const int idx = q4 * 256 + tid;
        const int b   = idx >> 4;           // 0..63
        const int cg  = idx & 15;           // 0..15
        const float4 v = *reinterpret_cast<const float4*>(
            &x[(size_t)(b0 + b) * 12288 + (size_t)(i * 3) * 64 + cg * 4]);
        const int col = cg * 4;
        const int sb  = b ^ ((cg & 7) << 2);
        xs[0][(col + 0) * 64 + sb] = v.x;
        xs[0][(col + 1) * 64 + sb] = v.y;
        xs[0][(col + 2) * 64 + sb] = v.z;
        xs[0][(col + 3) * 64 + sb] = v.w;
    }
    if (tid < 100)
        reinterpret_cast<float4*>(wu2[0])[tid] = wuc4[jw * 75 + tap];
    __syncthreads();

    float au[4][5], ap[4][5], ag[5];
    #pragma unroll
    for (int o = 0; o < 4; ++o)
        #pragma unroll
        for (int jj = 0; jj < 5; ++jj) { au[o][jj] = 0.f; ap[o][jj] = 0.f; }
    #pragma unroll
    for (int jj = 0; jj < 5; ++jj) ag[jj] = 0.f;

    #pragma unroll 1
    for (int p = 0; p < 15; ++p) {
        // ---- A) issue next phase's global loads (drain under compute) ----
        float4 nv0, nv1, nv2, nv3, nw;
        if (p < 14) {
            const int pn = p + 1;
            const int cn = pn / 5;
            const int an = pn - cn * 5;
            const size_t roff = (size_t)cn * 4096 + (size_t)(i * 3 + an) * 64;
            {   const int idx = tid;        const int b = idx >> 4, cg = idx & 15;
                nv0 = *reinterpret_cast<const float4*>(&x[(size_t)(b0 + b) * 12288 + roff + cg * 4]); }
            {   const int idx = 256 + tid;  const int b = idx >> 4, cg = idx & 15;
                nv1 = *reinterpret_cast<const float4*>(&x[(size_t)(b0 + b) * 12288 + roff + cg * 4]); }
            {   const int idx = 512 + tid;  const int b = idx >> 4, cg = idx & 15;
                nv2 = *reinterpret_cast<const float4*>(&x[(size_t)(b0 + b) * 12288 + roff + cg * 4]); }
            {   const int idx = 768 + tid;  const int b = idx >> 4, cg = idx & 15;
                nv3 = *reinterpret_cast<const float4*>(&x[(size_t)(b0 + b) * 12288 + roff + cg * 4]); }
            if (tid < 100) nw = wuc4[jw * 75 + pn * 5 + tap];
        }

        // ---- B) compute phase p from xs[p&1], wu2[p&1] (pure LDS+VALU) ----
        const float* xbuf = xs[p & 1];
        const float* wbuf = wu2[p & 1];
        float xv[17];
        #pragma unroll
        for (int t = 0; t < 17; ++t) {
            const int col = wkr * 15 + t;
            xv[t] = xbuf[col * 64 + (lane ^ (((col >> 2) & 7) << 2))];
        }
        const int n0 = p * 5;               // = c*25 + a*5
        #pragma unroll
        for (int b2 = 0; b2 < 5; ++b2) {
            const float  wlv = wl_s[n0 + b2];
            const float4 wp4 = *reinterpret_cast<const float4*>(&wp_s[(n0 + b2) * 4]);
            #pragma unroll
            for (int jj = 0; jj < 5; ++jj) {
                const float v = xv[3 * jj + b2];
                const float4 w4 = *reinterpret_cast<const float4*>(
                    &wbuf[((wkr * 5 + jj) * 5 + b2) * 4]);   // LDS broadcast
                ag[jj]    += v * wlv;
                au[0][jj] += v * w4.x;  au[1][jj] += v * w4.y;
                au[2][jj] += v * w4.z;  au[3][jj] += v * w4.w;
                ap[0][jj] += v * wp4.x; ap[1][jj] += v * wp4.y;
                ap[2][jj] += v * wp4.z; ap[3][jj] += v * wp4.w;
            }
        }

        // ---- C) write staged data into buffers [(p+1)&1] ----
        if (p < 14) {
            float* dstb = xs[(p + 1) & 1];
            {   const int idx = tid;        const int b = idx >> 4, cg = idx & 15;
                const int col = cg * 4, sb = b ^ ((cg & 7) << 2);
                dstb[(col+0)*64+sb] = nv0.x; dstb[(col+1)*64+sb] = nv0.y;
                dstb[(col+2)*64+sb] = nv0.z; dstb[(col+3)*64+sb] = nv0.w; }
            {   const int idx = 256 + tid;  const int b = idx >> 4, cg = idx & 15;
                const int col = cg * 4, sb = b ^ ((cg & 7) << 2);
                dstb[(col+0)*64+sb] = nv1.x; dstb[(col+1)*64+sb] = nv1.y;
                dstb[(col+2)*64+sb] = nv1.z; dstb[(col+3)*64+sb] = nv1.w; }
            {   const int idx = 512 + tid;  const int b = idx >> 4, cg = idx & 15;
                const int col = cg * 4, sb = b ^ ((cg & 7) << 2);
                dstb[(col+0)*64+sb] = nv2.x; dstb[(col+1)*64+sb] = nv2.y;
                dstb[(col+2)*64+sb] = nv2.z; dstb[(col+3)*64+sb] = nv2.w; }
            {   const int idx = 768 + tid;  const int b = idx >> 4, cg = idx & 15;
                const int col = cg * 4, sb = b ^ ((cg & 7) << 2);
                dstb[(col+0)*64+sb] = nv3.x; dstb[(col+1)*64+sb] = nv3.y;
                dstb[(col+2)*64+sb] = nv3.z; dstb[(col+3)*64+sb] = nv3.w; }
            if (tid < 100)
                reinterpret_cast<float4*>(wu2[(p + 1) & 1])[tid] = nw;
        }
        __syncthreads();
    }

    // ---- epilogue: gate blend + ReLU, batch-last coalesced stores ----
    const float bwl = b_wl[0];
    #pragma unroll
    for (int jj = 0; jj < 5; ++jj) {
        const int l = i * 20 + wkr * 5 + jj;
        const float g = sigmoidf_(ag[jj] + bwl);
        #pragma unroll
        for (int o = 0; o < 4; ++o) {
            const float x1 = au[o][jj] + b_uc[o * 400 + l];
            const float x2 = ap[o][jj] + b_pc[o];
            y1t[(size_t)(o * 400 + l) * B + b0 + lane] =
                fmaxf(x1 * g + x2 * (1.f - g), 0.f);
        }
    }
}

// ------------- batch-last block kernel: wave owns one location l ----------
template<int CIN, int COUT, int K, int S, int OH, int IH, int VB>
__global__ __launch_bounds__(256)
void blockT_kernel(const float* __restrict__ in_t,
                   const float* __restrict__ w_uc,  // (L*LN, COUT)
                   const float* __restrict__ b_uc,  // (COUT*L)
                   const float* __restrict__ w_pc,  // (COUT, LN)
                   const float* __restrict__ b_pc,  // (COUT)
                   const float* __restrict__ w_wl,  // (LN)
                   const float* __restrict__ b_wl,  // (1)
                   float* __restrict__ out_t,
                   int B)
{
    constexpr int LN = CIN * K * K;
    constexpr int L  = OH * OH;
    const int wv   = threadIdx.x >> 6;
    const int lane = threadIdx.x & 63;
    const int l    = __builtin_amdgcn_readfirstlane(blockIdx.y * 4 + wv);
    if (l >= L) return;
    const int i = l / OH, j = l % OH;
    const int b = blockIdx.x * (64 * VB) + lane * VB;

    float au[COUT][VB], ap[COUT][VB], ag[VB];
    #pragma unroll
    for (int o = 0; o < COUT; ++o)
        #pragma unroll
        for (int q = 0; q < VB; ++q) { au[o][q] = 0.f; ap[o][q] = 0.f; }
    #pragma unroll
    for (int q = 0; q < VB; ++q) ag[q] = 0.f;

    const float* wu = w_uc + (size_t)l * LN * COUT;

    #pragma unroll
    for (int c = 0; c < CIN; ++c)
    #pragma unroll
    for (int a = 0; a < K; ++a)
    #pragma unroll
    for (int b2 = 0; b2 < K; ++b2) {
        const int n = c * K * K + a * K + b2;
        const int p = c * IH * IH + (i * S + a) * IH + (j * S + b2);
        float v[VB];
        const float* src = in_t + (size_t)p * B + b;
        if constexpr (VB == 4) {
            const float4 t = *reinterpret_cast<const float4*>(src);
            v[0] = t.x; v[1] = t.y; v[2] = t.z; v[3] = t.w;
        } else if constexpr (VB == 2) {
            const float2 t = *reinterpret_cast<const float2*>(src);
            v[0] = t.x; v[1] = t.y;
        } else {
            v[0] = src[0];
        }
        const float wl = w_wl[n];
        #pragma unroll
        for (int q = 0; q < VB; ++q) ag[q] += v[q] * wl;
        #pragma unroll
        for (int o = 0; o < COUT; ++o) {
            const float wuv = wu[n * COUT + o];
            const float wpv = w_pc[o * LN + n];
            #pragma unroll
            for (int q = 0; q < VB; ++q) {
                au[o][q] += v[q] * wuv;
                ap[o][q] += v[q] * wpv;
            }
        }
    }

    const float bwl = b_wl[0];
    float g[VB];
    #pragma unroll
    for (int q = 0; q < VB; ++q) g[q] = sigmoidf_(ag[q] + bwl);

    #pragma unroll
    for (int o = 0; o < COUT; ++o) {
        const float buc = b_uc[o * L + l];
        const float bpc = b_pc[o];
        float y[VB];
        #pragma unroll
        for (int q = 0; q < VB; ++q) {
            const float x1 = au[o][q] + buc;
            const float x2 = ap[o][q] + bpc;
            y[q] = fmaxf(x1 * g[q] + x2 * (1.f - g[q]), 0.f);
        }
        float* dst = out_t + (size_t)(o * L + l) * B + b;
        if constexpr (VB == 4) {
            float4 t; t.x = y[0]; t.y = y[1]; t.z = y[2]; t.w = y[3];
            *reinterpret_cast<float4*>(dst) = t;
        } else if constexpr (VB == 2) {
            float2 t; t.x = y[0]; t.y = y[1];
            *reinterpret_cast<float2*>(dst) = t;
        } else {
            dst[0] = y[0];
        }
    }
}

// ---------- block4 (cin=16,k=3,s=2,oh=1,cout=32) + FC(32->4), batch-last ---
__global__ __launch_bounds__(256)
void block4T_fc(const float* __restrict__ in_t,  // (256, B)
                const float* __restrict__ w_uc,  // (144,32)
                const float* __restrict__ b_uc,  // (32)
                const float* __restrict__ w_pc,  // (32,144)
                const float* __restrict__ b_pc,  // (32)
                const float* __restrict__ w_wl,  // (144)
                const float* __restrict__ b_wl,  // (1)
                const float* __restrict__ fc_w,  // (32,4)
                const float* __restrict__ fc_b,  // (4)
                float* __restrict__ out,         // (B,4)
                int B)
{
    __shared__ __align__(16) float wu_s[144 * 36];
    __shared__ __align__(16) float wp_s[144 * 36];
    __shared__ float wl_s[144];
    __shared__ float buc_s[32], bpc_s[32], fcw_s[128], fcb_s[4];
    __shared__ float red[4][64][5];

    const int tid  = threadIdx.x;
    const int wv   = tid >> 6;
    const int lane = tid & 63;
    const int o0   = __builtin_amdgcn_readfirstlane(wv * 8);
    const int b    = blockIdx.x * 64 + lane;

    for (int idx = tid; idx < 144 * 32; idx += 256) {
        wu_s[(idx >> 5) * 36 + (idx & 31)] = w_uc[idx];
        const int o = idx / 144, n = idx - o * 144;
        wp_s[n * 36 + o] = w_pc[idx];
    }
    if (tid < 144) wl_s[tid] = w_wl[tid];
    if (tid < 32)  { buc_s[tid] = b_uc[tid]; bpc_s[tid] = b_pc[tid]; }
    if (tid >= 64 && tid < 192) fcw_s[tid - 64] = fc_w[tid - 64];
    if (tid >= 192 && tid < 196) fcb_s[tid - 192] = fc_b[tid - 192];
    __syncthreads();

    float au[8], apc[8], ag = 0.f;
    #pragma unroll
    for (int oo = 0; oo < 8; ++oo) { au[oo] = 0.f; apc[oo] = 0.f; }

    #pragma unroll
    for (int c = 0; c < 16; ++c) {
        float v[9];
        #pragma unroll
        for (int a = 0; a < 3; ++a)
        #pragma unroll
        for (int b2 = 0; b2 < 3; ++b2)
            v[a * 3 + b2] = in_t[(size_t)(c * 16 + a * 4 + b2) * B + b];

        #pragma unroll
        for (int t = 0; t < 9; ++t) {
            const int n = c * 9 + t;
            ag += v[t] * wl_s[n];
            const float4 wuA = *reinterpret_cast<const float4*>(&wu_s[n * 36 + o0]);
            const float4 wuB = *reinterpret_cast<const float4*>(&wu_s[n * 36 + o0 + 4]);
            const float4 wpA = *reinterpret_cast<const float4*>(&wp_s[n * 36 + o0]);
            const float4 wpB = *reinterpret_cast<const float4*>(&wp_s[n * 36 + o0 + 4]);
            au[0] += v[t] * wuA.x;  au[1] += v[t] * wuA.y;
            au[2] += v[t] * wuA.z;  au[3] += v[t] * wuA.w;
            au[4] += v[t] * wuB.x;  au[5] += v[t] * wuB.y;
            au[6] += v[t] * wuB.z;  au[7] += v[t] * wuB.w;
            apc[0] += v[t] * wpA.x; apc[1] += v[t] * wpA.y;
            apc[2] += v[t] * wpA.z; apc[3] += v[t] * wpA.w;
            apc[4] += v[t] * wpB.x; apc[5] += v[t] * wpB.y;
            apc[6] += v[t] * wpB.z; apc[7] += v[t] * wpB.w;
        }
    }

    const float g = sigmoidf_(ag + b_wl[0]);
    float pf[4] = {0.f, 0.f, 0.f, 0.f};
    #pragma unroll
    for (int oo = 0; oo < 8; ++oo) {
        const int o = o0 + oo;
        const float h = fmaxf((au[oo] + buc_s[o]) * g +
                              (apc[oo] + bpc_s[o]) * (1.f - g), 0.f);
        #pragma unroll
        for (int f = 0; f < 4; ++f) pf[f] += h * fcw_s[o * 4 + f];
    }
    #pragma unroll
    for (int f = 0; f < 4; ++f) red[wv][lane][f] = pf[f];
    __syncthreads();
    if (wv == 0) {
        float4 s;
        s.x = fcb_s[0] + red[0][lane][0] + red[1][lane][0] + red[2][lane][0] + red[3][lane][0];
        s.y = fcb_s[1] + red[0][lane][1] + red[1][lane][1] + red[2][lane][1] + red[3][lane][1];
        s.z = fcb_s[2] + red[0][lane][2] + red[1][lane][2] + red[2][lane][2] + red[3][lane][2];
        s.w = fcb_s[3] + red[0][lane][3] + red[1][lane][3] + red[2][lane][3] + red[3][lane][3];
        *reinterpret_cast<float4*>(out + (size_t)b * 4) = s;
    }
}

// ======================= fallback path (round-1, NCHW) ====================
template<int CIN, int COUT, int K, int S, int OH, int IH, int BPB>
__global__ __launch_bounds__(256)
void block_kernel(const float* __restrict__ in,
                  const float* __restrict__ w_uc,
                  const float* __restrict__ b_uc,
                  const float* __restrict__ w_pc,
                  const float* __restrict__ b_pc,
                  const float* __restrict__ w_wl,
                  const float* __restrict__ b_wl,
                  float* __restrict__ out,
                  int B)
{
    constexpr int LN   = CIN * K * K;
    constexpr int L    = OH * OH;
    constexpr int TILE = CIN * IH * IH;
    __shared__ __align__(16) float lds[BPB * TILE];

    const int b0 = blockIdx.x * BPB;
    const int nb = (B - b0 < BPB) ? (B - b0) : BPB;
    const int tot = nb * TILE;
    const float* src = in + (size_t)b0 * TILE;
    if ((tot & 3) == 0) {
        const float4* s4 = reinterpret_cast<const float4*>(src);
        float4* d4 = reinterpret_cast<float4*>(lds);
        for (int idx = threadIdx.x; idx < (tot >> 2); idx += blockDim.x) d4[idx] = s4[idx];
    } else {
        for (int idx = threadIdx.x; idx < tot; idx += blockDim.x) lds[idx] = src[idx];
    }
    __syncthreads();

    const float bwl = b_wl[0];
    for (int t = threadIdx.x; t < nb * L; t += blockDim.x) {
        const int bb = t / L;
        const int l  = t % L;
        const int i  = l / OH, j = l % OH;
        const float* tile = lds + bb * TILE;

        float acc_uc[COUT], acc_pc[COUT];
        #pragma unroll
        for (int o = 0; o < COUT; ++o) { acc_uc[o] = 0.f; acc_pc[o] = 0.f; }
        float acc_g = 0.f;

        const float* wu = w_uc + (size_t)l * LN * COUT;
        #pragma unroll
        for (int c = 0; c < CIN; ++c)
        #pragma unroll
        for (int a = 0; a < K; ++a)
        #pragma unroll
        for (int b2 = 0; b2 < K; ++b2) {
            const int n = c * K * K + a * K + b2;
            const float v = tile[c * IH * IH + (i * S + a) * IH + (j * S + b2)];
            acc_g += v * w_wl[n];
            #pragma unroll
            for (int o = 0; o < COUT; ++o) acc_uc[o] += v * wu[n * COUT + o];
            #pragma unroll
            for (int o = 0; o < COUT; ++o) acc_pc[o] += v * w_pc[o * LN + n];
        }

        const float g = sigmoidf_(acc_g + bwl);
        const size_t ob = (size_t)(b0 + bb) * COUT * L;
        #pragma unroll
        for (int o = 0; o < COUT; ++o) {
            const float x1 = acc_uc[o] + b_uc[o * L + l];
            const float x2 = acc_pc[o] + b_pc[o];
            out[ob + o * L + l] = fmaxf(x1 * g + x2 * (1.f - g), 0.f);
        }
    }
}

__global__ __launch_bounds__(256)
void block4_fc_kernel(const float* __restrict__ in,
                      const float* __restrict__ w_uc,
                      const float* __restrict__ b_uc,
                      const float* __restrict__ w_pc,
                      const float* __restrict__ b_pc,
                      const float* __restrict__ w_wl,
                      const float* __restrict__ b_wl,
                      const float* __restrict__ fc_w,
                      const float* __restrict__ fc_b,
                      float* __restrict__ out,
                      int B)
{
    __shared__ float hbuf[8][32];
    const int bl = threadIdx.x >> 5;
    const int o  = threadIdx.x & 31;
    const int b  = blockIdx.x * 8 + bl;

    if (b < B) {
        const float* xb = in + (size_t)b * 256;
        float acc_uc = 0.f, acc_pc = 0.f, acc_g = 0.f;
        #pragma unroll
        for (int c = 0; c < 16; ++c)
        #pragma unroll
        for (int a = 0; a < 3; ++a)
        #pragma unroll
        for (int b2 = 0; b2 < 3; ++b2) {
            const int n = c * 9 + a * 3 + b2;
            const float v = xb[c * 16 + a * 4 + b2];
            acc_uc += v * w_uc[n * 32 + o];
            acc_pc += v * w_pc[o * 144 + n];
            acc_g  += v * w_wl[n];
        }
        const float g  = sigmoidf_(acc_g + b_wl[0]);
        hbuf[bl][o] = fmaxf((acc_uc + b_uc[o]) * g + (acc_pc + b_pc[o]) * (1.f - g), 0.f);
    }
    __syncthreads();

    if (threadIdx.x < 32) {
        const int bl2 = threadIdx.x >> 2;
        const int f   = threadIdx.x & 3;
        const int bb  = blockIdx.x * 8 + bl2;
        if (bb < B) {
            float s = fc_b[f];
            #pragma unroll
            for (int oo = 0; oo < 32; ++oo) s += hbuf[bl2][oo] * fc_w[oo * 4 + f];
            out[(size_t)bb * 4 + f] = s;
        }
    }
}

// ==========================================================================
extern "C" void kernel_launch(void* const* d_in, const int* in_sizes, int n_in,
                              void* d_out, int out_size, void* d_ws, size_t ws_size,
                              hipStream_t stream) {
    const float* x    = (const float*)d_in[0];
    const float* wuc1 = (const float*)d_in[1];
    const float* buc1 = (const float*)d_in[2];
    const float* wpc1 = (const float*)d_in[3];
    const float* bpc1 = (const float*)d_in[4];
    const float* wwl1 = (const float*)d_in[5];
    const float* bwl1 = (const float*)d_in[6];
    const float* wuc2 = (const float*)d_in[7];
    const float* buc2 = (const float*)d_in[8];
    const float* wpc2 = (const float*)d_in[9];
    const float* bpc2 = (const float*)d_in[10];
    const float* wwl2 = (const float*)d_in[11];
    const float* bwl2 = (const float*)d_in[12];
    const float* wuc3 = (const float*)d_in[13];
    const float* buc3 = (const float*)d_in[14];
    const float* wpc3 = (const float*)d_in[15];
    const float* bpc3 = (const float*)d_in[16];
    const float* wwl3 = (const float*)d_in[17];
    const float* bwl3 = (const float*)d_in[18];
    const float* wuc4 = (const float*)d_in[19];
    const float* buc4 = (const float*)d_in[20];
    const float* wpc4 = (const float*)d_in[21];
    const float* bpc4 = (const float*)d_in[22];
    const float* wwl4 = (const float*)d_in[23];
    const float* bwl4 = (const float*)d_in[24];
    const float* fcw  = (const float*)d_in[25];
    const float* fcb  = (const float*)d_in[26];

    const int B = in_sizes[0] / (3 * 64 * 64);   // 2048
    float* ws = (float*)d_ws;
    const size_t need = sizeof(float) * (size_t)(1600 + 486 + 256) * B;

    if (ws_size >= need && (B % 256) == 0) {
        // ---------------- batch-last fast path (fused block1 v5) ----------
        float* y1 = ws;                             // (1600, B)
        float* y2 = y1 + (size_t)1600 * B;          // (486, B)
        float* y3 = y2 + (size_t)486 * B;           // (256, B)

        block1_fused5<<<dim3(B / 64, 20), 256, 0, stream>>>(
            x, wuc1, buc1, wpc1, bpc1, wwl1, bwl1, y1, B);
        blockT_kernel<4, 6, 3, 2, 9, 20, 2>
            <<<dim3(B / 128, 21), 256, 0, stream>>>(y1, wuc2, buc2, wpc2, bpc2, wwl2, bwl2, y2, B);
        blockT_kernel<6, 16, 3, 2, 4, 9, 1>
            <<<dim3(B / 64, 4), 256, 0, stream>>>(y2, wuc3, buc3, wpc3, bpc3, wwl3, bwl3, y3, B);
        block4T_fc<<<B / 64, 256, 0, stream>>>(y3, wuc4, buc4, wpc4, bpc4, wwl4, bwl4,
                                               fcw, fcb, (float*)d_out, B);
    } else {
        // ---------------- fallback (round-1) ----------------
        float* y1 = ws;
        float* y2 = y1 + (size_t)B * 4 * 400;
        float* y3 = y2 + (size_t)B * 6 * 81;
        block_kernel<3, 4, 5, 3, 20, 64, 1>
            <<<B, 256, 0, stream>>>(x, wuc1, buc1, wpc1, bpc1, wwl1, bwl1, y1, B);
        block_kernel<4, 6, 3, 2, 9, 20, 4>
            <<<(B + 3) / 4, 256, 0, stream>>>(y1, wuc2, buc2, wpc2, bpc2, wwl2, bwl2, y2, B);
        block_kernel<6, 16, 3, 2, 4, 9, 16>
            <<<(B + 15) / 16, 256, 0, stream>>>(y2, wuc3, buc3, wpc3, bpc3, wwl3, bwl3, y3, B);
        block4_fc_kernel<<<(B + 7) / 8, 256, 0, stream>>>(
            y3, wuc4, buc4, wpc4, bpc4, wwl4, bwl4, fcw, fcb, (float*)d_out, B);
    }
}

// Round 11
// 106.753 us; speedup vs baseline: 1.2543x; 1.0696x over previous
//
#include <hip/hip_runtime.h>
#include <math.h>

// BlockNet: 4× (unfold-linear ⊕ conv ⊕ sigmoid-gate blend, ReLU) + FC(32->4).
// Round 11: block1_fused6 — VB=2 (each lane owns 2 batches) to halve the
// per-FLOP weight-LDS traffic (25 ds_read_b128 now feed 8 FMAs each).
// 128-thread WGs (2 waves x 5 j's = one j-half), 128 batches, grid
// (B/128, 40) = 640 balanced WGs. Single-buffered x (v3b pattern; dbuf
// measured no-win in v5). Weights in LDS (VMEM weights regressed in v4).
// CFG: (cin,cout,k,s,oh) = (3,4,5,3,20),(4,6,3,2,9),(6,16,3,2,4),(16,32,3,2,1)

__device__ __forceinline__ float sigmoidf_(float x) {
    return 1.0f / (1.0f + expf(-x));
}

// ---------------------------------------------------------------------------
// block1 fused v6: grid (B/128, 40), 128 threads (2 waves).
// blockIdx.y -> i = y>>1 (output row), jh = y&1 (j-half: j in [10jh,10jh+10)).
// Wave jg owns j in [10jh+5jg, +5). lane = batch; each lane also handles
// batch lane+64 (VB=2). 15 phases (c,a): stage 36-col x row slice
// [coloff, coloff+36) into xs[lc][h*64 + swz(bl)], then 25 taps x 5 j x 2 b.
__global__ __launch_bounds__(128)
void block1_fused6(const float* __restrict__ x,     // (B,3,64,64)
                   const float* __restrict__ w_uc,  // (400*75, 4)
                   const float* __restrict__ b_uc,  // (4*400)
                   const float* __restrict__ w_pc,  // (4,75)
                   const float* __restrict__ b_pc,  // (4)
                   const float* __restrict__ w_wl,  // (75)
                   const float* __restrict__ b_wl,  // (1)
                   float* __restrict__ y1t,         // (1600, B)
                   int B)
{
    __shared__ __align__(16) float xs[36 * 128];    // [lc][h*64 + swz(bl)]
    __shared__ __align__(16) float wu_s[3000];      // [jrel][n][o], 10 j's
    __shared__ __align__(16) float wp_s[300];       // [n][o]
    __shared__ float wl_s[75];

    const int tid  = threadIdx.x;                   // 0..127
    const int lane = tid & 63;
    const int jg   = __builtin_amdgcn_readfirstlane(tid >> 6);  // 0..1
    const int b0   = blockIdx.x * 128;
    const int i    = blockIdx.y >> 1;               // output row
    const int jh   = blockIdx.y & 1;                // j-half
    const int coloff = jh ? 28 : 0;                 // 16B-aligned tile origin

    // ---- stage weights once (strided loops; published by first barrier) ----
    {
        const float4* src = reinterpret_cast<const float4*>(w_uc)
                          + (size_t)(i * 20 + jh * 10) * 75;    // 750 f4
        float4* dst = reinterpret_cast<float4*>(wu_s);
        for (int idx = tid; idx < 750; idx += 128) dst[idx] = src[idx];
        for (int idx = tid; idx < 300; idx += 128)
            wp_s[idx] = w_pc[(idx & 3) * 75 + (idx >> 2)];      // [n][o]
        for (int idx = tid; idx < 75; idx += 128) wl_s[idx] = w_wl[idx];
    }

    float au[4][5][2], ap[4][5][2], ag[5][2];
    #pragma unroll
    for (int o = 0; o < 4; ++o)
        #pragma unroll
        for (int jj = 0; jj < 5; ++jj) {
            au[o][jj][0] = 0.f; au[o][jj][1] = 0.f;
            ap[o][jj][0] = 0.f; ap[o][jj][1] = 0.f;
        }
    #pragma unroll
    for (int jj = 0; jj < 5; ++jj) { ag[jj][0] = 0.f; ag[jj][1] = 0.f; }

    const int lcbase = jg * 15 + (jh ? 2 : 0);

    #pragma unroll 1
    for (int p = 0; p < 15; ++p) {
        const int c = p / 5;
        const int a = p - c * 5;
        __syncthreads();   // previous compute done before overwrite

        // ---- stage 36 cols x 128 batches: 1152 f4, 9 per thread ----
        // idx in [0,1152): b = idx/9 (magic mul), cg = idx%9; global col
        // group = coloff + cg*4 (16B aligned). Write through v3b swizzle.
        const size_t rbase = (size_t)c * 4096 + (size_t)(i * 3 + a) * 64 + coloff;
        #pragma unroll
        for (int it = 0; it < 9; ++it) {
            const int idx = it * 128 + tid;
            const int b   = (int)(((unsigned)idx * 7282u) >> 16);   // idx/9
            const int cg  = idx - b * 9;                            // 0..8
            const float4 v = *reinterpret_cast<const float4*>(
                &x[(size_t)(b0 + b) * 12288 + rbase + cg * 4]);
            const int h  = b >> 6;
            const int bl = b & 63;
            const int sw = (cg & 7) << 2;       // = ((lc>>2)&7)<<2 for lc=cg*4+k
            const int lc = cg * 4;
            const int base = h * 64 + (bl ^ sw);
            xs[(lc + 0) * 128 + base] = v.x;
            xs[(lc + 1) * 128 + base] = v.y;
            xs[(lc + 2) * 128 + base] = v.z;
            xs[(lc + 3) * 128 + base] = v.w;
        }
        __syncthreads();

        // ---- compute: 17 cols x 2 halves into regs, then 25 taps ----
        float xv0[17], xv1[17];
        #pragma unroll
        for (int t = 0; t < 17; ++t) {
            const int lc = lcbase + t;
            const int sw = ((lc >> 2) & 7) << 2;
            xv0[t] = xs[lc * 128 + (lane ^ sw)];
            xv1[t] = xs[lc * 128 + 64 + (lane ^ sw)];
        }
        const int n0 = p * 5;                   // = c*25 + a*5
        #pragma unroll
        for (int b2 = 0; b2 < 5; ++b2) {
            const float  wlv = wl_s[n0 + b2];
            const float4 wp4 = *reinterpret_cast<const float4*>(&wp_s[(n0 + b2) * 4]);
            #pragma unroll
            for (int jj = 0; jj < 5; ++jj) {
                const float4 w4 = *reinterpret_cast<const float4*>(
                    &wu_s[((jg * 5 + jj) * 75 + n0 + b2) * 4]);  // LDS broadcast
                const float v0 = xv0[3 * jj + b2];
                const float v1 = xv1[3 * jj + b2];
                ag[jj][0]    += v0 * wlv;   ag[jj][1]    += v1 * wlv;
                au[0][jj][0] += v0 * w4.x;  au[0][jj][1] += v1 * w4.x;
                au[1][jj][0] += v0 * w4.y;  au[1][jj][1] += v1 * w4.y;
                au[2][jj][0] += v0 * w4.z;  au[2][jj][1] += v1 * w4.z;
                au[3][jj][0] += v0 * w4.w;  au[3][jj][1] += v1 * w4.w;
                ap[0][jj][0] += v0 * wp4.x; ap[0][jj][1] += v1 * wp4.x;
                ap[1][jj][0] += v0 * wp4.y; ap[1][jj][1] += v1 * wp4.y;
                ap[2][jj][0] += v0 * wp4.z; ap[2][jj][1] += v1 * wp4.z;
                ap[3][jj][0] += v0 * wp4.w; ap[3][jj][1] += v1 * wp4.w;
            }
        }
    }

    // ---- epilogue: gate blend + ReLU, batch-last coalesced stores ----
    const float bwl = b_wl[0];
    #pragma unroll
    for (int jj = 0; jj < 5; ++jj) {
        const int l = i * 20 + jh * 10 + jg * 5 + jj;
        #pragma unroll
        for (int h = 0; h < 2; ++h) {
            const float g = sigmoidf_(ag[jj][h] + bwl);
            #pragma unroll
            for (int o = 0; o < 4; ++o) {
                const float x1 = au[o][jj][h] + b_uc[o * 400 + l];
                const float x2 = ap[o][jj][h] + b_pc[o];
                y1t[(size_t)(o * 400 + l) * B + b0 + h * 64 + lane] =
                    fmaxf(x1 * g + x2 * (1.f - g), 0.f);
            }
        }
    }
}

// ------------- batch-last block kernel: wave owns one location l ----------
template<int CIN, int COUT, int K, int S, int OH, int IH, int VB>
__global__ __launch_bounds__(256)
void blockT_kernel(const float* __restrict__ in_t,
                   const float* __restrict__ w_uc,  // (L*LN, COUT)
                   const float* __restrict__ b_uc,  // (COUT*L)
                   const float* __restrict__ w_pc,  // (COUT, LN)
                   const float* __restrict__ b_pc,  // (COUT)
                   const float* __restrict__ w_wl,  // (LN)
                   const float* __restrict__ b_wl,  // (1)
                   float* __restrict__ out_t,
                   int B)
{
    constexpr int LN = CIN * K * K;
    constexpr int L  = OH * OH;
    const int wv   = threadIdx.x >> 6;
    const int lane = threadIdx.x & 63;
    const int l    = __builtin_amdgcn_readfirstlane(blockIdx.y * 4 + wv);
    if (l >= L) return;
    const int i = l / OH, j = l % OH;
    const int b = blockIdx.x * (64 * VB) + lane * VB;

    float au[COUT][VB], ap[COUT][VB], ag[VB];
    #pragma unroll
    for (int o = 0; o < COUT; ++o)
        #pragma unroll
        for (int q = 0; q < VB; ++q) { au[o][q] = 0.f; ap[o][q] = 0.f; }
    #pragma unroll
    for (int q = 0; q < VB; ++q) ag[q] = 0.f;

    const float* wu = w_uc + (size_t)l * LN * COUT;

    #pragma unroll
    for (int c = 0; c < CIN; ++c)
    #pragma unroll
    for (int a = 0; a < K; ++a)
    #pragma unroll
    for (int b2 = 0; b2 < K; ++b2) {
        const int n = c * K * K + a * K + b2;
        const int p = c * IH * IH + (i * S + a) * IH + (j * S + b2);
        float v[VB];
        const float* src = in_t + (size_t)p * B + b;
        if constexpr (VB == 4) {
            const float4 t = *reinterpret_cast<const float4*>(src);
            v[0] = t.x; v[1] = t.y; v[2] = t.z; v[3] = t.w;
        } else if constexpr (VB == 2) {
            const float2 t = *reinterpret_cast<const float2*>(src);
            v[0] = t.x; v[1] = t.y;
        } else {
            v[0] = src[0];
        }
        const float wl = w_wl[n];
        #pragma unroll
        for (int q = 0; q < VB; ++q) ag[q] += v[q] * wl;
        #pragma unroll
        for (int o = 0; o < COUT; ++o) {
            const float wuv = wu[n * COUT + o];
            const float wpv = w_pc[o * LN + n];
            #pragma unroll
            for (int q = 0; q < VB; ++q) {
                au[o][q] += v[q] * wuv;
                ap[o][q] += v[q] * wpv;
            }
        }
    }

    const float bwl = b_wl[0];
    float g[VB];
    #pragma unroll
    for (int q = 0; q < VB; ++q) g[q] = sigmoidf_(ag[q] + bwl);

    #pragma unroll
    for (int o = 0; o < COUT; ++o) {
        const float buc = b_uc[o * L + l];
        const float bpc = b_pc[o];
        float y[VB];
        #pragma unroll
        for (int q = 0; q < VB; ++q) {
            const float x1 = au[o][q] + buc;
            const float x2 = ap[o][q] + bpc;
            y[q] = fmaxf(x1 * g[q] + x2 * (1.f - g[q]), 0.f);
        }
        float* dst = out_t + (size_t)(o * L + l) * B + b;
        if constexpr (VB == 4) {
            float4 t; t.x = y[0]; t.y = y[1]; t.z = y[2]; t.w = y[3];
            *reinterpret_cast<float4*>(dst) = t;
        } else if constexpr (VB == 2) {
            float2 t; t.x = y[0]; t.y = y[1];
            *reinterpret_cast<float2*>(dst) = t;
        } else {
            dst[0] = y[0];
        }
    }
}

// ---------- block4 (cin=16,k=3,s=2,oh=1,cout=32) + FC(32->4), batch-last ---
__global__ __launch_bounds__(256)
void block4T_fc(const float* __restrict__ in_t,  // (256, B)
                const float* __restrict__ w_uc,  // (144,32)
                const float* __restrict__ b_uc,  // (32)
                const float* __restrict__ w_pc,  // (32,144)
                const float* __restrict__ b_pc,  // (32)
                const float* __restrict__ w_wl,  // (144)
                const float* __restrict__ b_wl,  // (1)
                const float* __restrict__ fc_w,  // (32,4)
                const float* __restrict__ fc_b,  // (4)
                float* __restrict__ out,         // (B,4)
                int B)
{
    __shared__ __align__(16) float wu_s[144 * 36];
    __shared__ __align__(16) float wp_s[144 * 36];
    __shared__ float wl_s[144];
    __shared__ float buc_s[32], bpc_s[32], fcw_s[128], fcb_s[4];
    __shared__ float red[4][64][5];

    const int tid  = threadIdx.x;
    const int wv   = tid >> 6;
    const int lane = tid & 63;
    const int o0   = __builtin_amdgcn_readfirstlane(wv * 8);
    const int b    = blockIdx.x * 64 + lane;

    for (int idx = tid; idx < 144 * 32; idx += 256) {
        wu_s[(idx >> 5) * 36 + (idx & 31)] = w_uc[idx];
        const int o = idx / 144, n = idx - o * 144;
        wp_s[n * 36 + o] = w_pc[idx];
    }
    if (tid < 144) wl_s[tid] = w_wl[tid];
    if (tid < 32)  { buc_s[tid] = b_uc[tid]; bpc_s[tid] = b_pc[tid]; }
    if (tid >= 64 && tid < 192) fcw_s[tid - 64] = fc_w[tid - 64];
    if (tid >= 192 && tid < 196) fcb_s[tid - 192] = fc_b[tid - 192];
    __syncthreads();

    float au[8], apc[8], ag = 0.f;
    #pragma unroll
    for (int oo = 0; oo < 8; ++oo) { au[oo] = 0.f; apc[oo] = 0.f; }

    #pragma unroll
    for (int c = 0; c < 16; ++c) {
        float v[9];
        #pragma unroll
        for (int a = 0; a < 3; ++a)
        #pragma unroll
        for (int b2 = 0; b2 < 3; ++b2)
            v[a * 3 + b2] = in_t[(size_t)(c * 16 + a * 4 + b2) * B + b];

        #pragma unroll
        for (int t = 0; t < 9; ++t) {
            const int n = c * 9 + t;
            ag += v[t] * wl_s[n];
            const float4 wuA = *reinterpret_cast<const float4*>(&wu_s[n * 36 + o0]);
            const float4 wuB = *reinterpret_cast<const float4*>(&wu_s[n * 36 + o0 + 4]);
            const float4 wpA = *reinterpret_cast<const float4*>(&wp_s[n * 36 + o0]);
            const float4 wpB = *reinterpret_cast<const float4*>(&wp_s[n * 36 + o0 + 4]);
            au[0] += v[t] * wuA.x;  au[1] += v[t] * wuA.y;
            au[2] += v[t] * wuA.z;  au[3] += v[t] * wuA.w;
            au[4] += v[t] * wuB.x;  au[5] += v[t] * wuB.y;
            au[6] += v[t] * wuB.z;  au[7] += v[t] * wuB.w;
            apc[0] += v[t] * wpA.x; apc[1] += v[t] * wpA.y;
            apc[2] += v[t] * wpA.z; apc[3] += v[t] * wpA.w;
            apc[4] += v[t] * wpB.x; apc[5] += v[t] * wpB.y;
            apc[6] += v[t] * wpB.z; apc[7] += v[t] * wpB.w;
        }
    }

    const float g = sigmoidf_(ag + b_wl[0]);
    float pf[4] = {0.f, 0.f, 0.f, 0.f};
    #pragma unroll
    for (int oo = 0; oo < 8; ++oo) {
        const int o = o0 + oo;
        const float h = fmaxf((au[oo] + buc_s[o]) * g +
                              (apc[oo] + bpc_s[o]) * (1.f - g), 0.f);
        #pragma unroll
        for (int f = 0; f < 4; ++f) pf[f] += h * fcw_s[o * 4 + f];
    }
    #pragma unroll
    for (int f = 0; f < 4; ++f) red[wv][lane][f] = pf[f];
    __syncthreads();
    if (wv == 0) {
        float4 s;
        s.x = fcb_s[0] + red[0][lane][0] + red[1][lane][0] + red[2][lane][0] + red[3][lane][0];
        s.y = fcb_s[1] + red[0][lane][1] + red[1][lane][1] + red[2][lane][1] + red[3][lane][1];
        s.z = fcb_s[2] + red[0][lane][2] + red[1][lane][2] + red[2][lane][2] + red[3][lane][2];
        s.w = fcb_s[3] + red[0][lane][3] + red[1][lane][3] + red[2][lane][3] + red[3][lane][3];
        *reinterpret_cast<float4*>(out + (size_t)b * 4) = s;
    }
}

// ======================= fallback path (round-1, NCHW) ====================
template<int CIN, int COUT, int K, int S, int OH, int IH, int BPB>
__global__ __launch_bounds__(256)
void block_kernel(const float* __restrict__ in,
                  const float* __restrict__ w_uc,
                  const float* __restrict__ b_uc,
                  const float* __restrict__ w_pc,
                  const float* __restrict__ b_pc,
                  const float* __restrict__ w_wl,
                  const float* __restrict__ b_wl,
                  float* __restrict__ out,
                  int B)
{
    constexpr int LN   = CIN * K * K;
    constexpr int L    = OH * OH;
    constexpr int TILE = CIN * IH * IH;
    __shared__ __align__(16) float lds[BPB * TILE];

    const int b0 = blockIdx.x * BPB;
    const int nb = (B - b0 < BPB) ? (B - b0) : BPB;
    const int tot = nb * TILE;
    const float* src = in + (size_t)b0 * TILE;
    if ((tot & 3) == 0) {
        const float4* s4 = reinterpret_cast<const float4*>(src);
        float4* d4 = reinterpret_cast<float4*>(lds);
        for (int idx = threadIdx.x; idx < (tot >> 2); idx += blockDim.x) d4[idx] = s4[idx];
    } else {
        for (int idx = threadIdx.x; idx < tot; idx += blockDim.x) lds[idx] = src[idx];
    }
    __syncthreads();

    const float bwl = b_wl[0];
    for (int t = threadIdx.x; t < nb * L; t += blockDim.x) {
        const int bb = t / L;
        const int l  = t % L;
        const int i  = l / OH, j = l % OH;
        const float* tile = lds + bb * TILE;

        float acc_uc[COUT], acc_pc[COUT];
        #pragma unroll
        for (int o = 0; o < COUT; ++o) { acc_uc[o] = 0.f; acc_pc[o] = 0.f; }
        float acc_g = 0.f;

        const float* wu = w_uc + (size_t)l * LN * COUT;
        #pragma unroll
        for (int c = 0; c < CIN; ++c)
        #pragma unroll
        for (int a = 0; a < K; ++a)
        #pragma unroll
        for (int b2 = 0; b2 < K; ++b2) {
            const int n = c * K * K + a * K + b2;
            const float v = tile[c * IH * IH + (i * S + a) * IH + (j * S + b2)];
            acc_g += v * w_wl[n];
            #pragma unroll
            for (int o = 0; o < COUT; ++o) acc_uc[o] += v * wu[n * COUT + o];
            #pragma unroll
            for (int o = 0; o < COUT; ++o) acc_pc[o] += v * w_pc[o * LN + n];
        }

        const float g = sigmoidf_(acc_g + bwl);
        const size_t ob = (size_t)(b0 + bb) * COUT * L;
        #pragma unroll
        for (int o = 0; o < COUT; ++o) {
            const float x1 = acc_uc[o] + b_uc[o * L + l];
            const float x2 = acc_pc[o] + b_pc[o];
            out[ob + o * L + l] = fmaxf(x1 * g + x2 * (1.f - g), 0.f);
        }
    }
}

__global__ __launch_bounds__(256)
void block4_fc_kernel(const float* __restrict__ in,
                      const float* __restrict__ w_uc,
                      const float* __restrict__ b_uc,
                      const float* __restrict__ w_pc,
                      const float* __restrict__ b_pc,
                      const float* __restrict__ w_wl,
                      const float* __restrict__ b_wl,
                      const float* __restrict__ fc_w,
                      const float* __restrict__ fc_b,
                      float* __restrict__ out,
                      int B)
{
    __shared__ float hbuf[8][32];
    const int bl = threadIdx.x >> 5;
    const int o  = threadIdx.x & 31;
    const int b  = blockIdx.x * 8 + bl;

    if (b < B) {
        const float* xb = in + (size_t)b * 256;
        float acc_uc = 0.f, acc_pc = 0.f, acc_g = 0.f;
        #pragma unroll
        for (int c = 0; c < 16; ++c)
        #pragma unroll
        for (int a = 0; a < 3; ++a)
        #pragma unroll
        for (int b2 = 0; b2 < 3; ++b2) {
            const int n = c * 9 + a * 3 + b2;
            const float v = xb[c * 16 + a * 4 + b2];
            acc_uc += v * w_uc[n * 32 + o];
            acc_pc += v * w_pc[o * 144 + n];
            acc_g  += v * w_wl[n];
        }
        const float g  = sigmoidf_(acc_g + b_wl[0]);
        hbuf[bl][o] = fmaxf((acc_uc + b_uc[o]) * g + (acc_pc + b_pc[o]) * (1.f - g), 0.f);
    }
    __syncthreads();

    if (threadIdx.x < 32) {
        const int bl2 = threadIdx.x >> 2;
        const int f   = threadIdx.x & 3;
        const int bb  = blockIdx.x * 8 + bl2;
        if (bb < B) {
            float s = fc_b[f];
            #pragma unroll
            for (int oo = 0; oo < 32; ++oo) s += hbuf[bl2][oo] * fc_w[oo * 4 + f];
            out[(size_t)bb * 4 + f] = s;
        }
    }
}

// ==========================================================================
extern "C" void kernel_launch(void* const* d_in, const int* in_sizes, int n_in,
                              void* d_out, int out_size, void* d_ws, size_t ws_size,
                              hipStream_t stream) {
    const float* x    = (const float*)d_in[0];
    const float* wuc1 = (const float*)d_in[1];
    const float* buc1 = (const float*)d_in[2];
    const float* wpc1 = (const float*)d_in[3];
    const float* bpc1 = (const float*)d_in[4];
    const float* wwl1 = (const float*)d_in[5];
    const float* bwl1 = (const float*)d_in[6];
    const float* wuc2 = (const float*)d_in[7];
    const float* buc2 = (const float*)d_in[8];
    const float* wpc2 = (const float*)d_in[9];
    const float* bpc2 = (const float*)d_in[10];
    const float* wwl2 = (const float*)d_in[11];
    const float* bwl2 = (const float*)d_in[12];
    const float* wuc3 = (const float*)d_in[13];
    const float* buc3 = (const float*)d_in[14];
    const float* wpc3 = (const float*)d_in[15];
    const float* bpc3 = (const float*)d_in[16];
    const float* wwl3 = (const float*)d_in[17];
    const float* bwl3 = (const float*)d_in[18];
    const float* wuc4 = (const float*)d_in[19];
    const float* buc4 = (const float*)d_in[20];
    const float* wpc4 = (const float*)d_in[21];
    const float* bpc4 = (const float*)d_in[22];
    const float* wwl4 = (const float*)d_in[23];
    const float* bwl4 = (const float*)d_in[24];
    const float* fcw  = (const float*)d_in[25];
    const float* fcb  = (const float*)d_in[26];

    const int B = in_sizes[0] / (3 * 64 * 64);   // 2048
    float* ws = (float*)d_ws;
    const size_t need = sizeof(float) * (size_t)(1600 + 486 + 256) * B;

    if (ws_size >= need && (B % 256) == 0) {
        // ---------------- batch-last fast path (fused block1 v6) ----------
        float* y1 = ws;                             // (1600, B)
        float* y2 = y1 + (size_t)1600 * B;          // (486, B)
        float* y3 = y2 + (size_t)486 * B;           // (256, B)

        block1_fused6<<<dim3(B / 128, 40), 128, 0, stream>>>(
            x, wuc1, buc1, wpc1, bpc1, wwl1, bwl1, y1, B);
        blockT_kernel<4, 6, 3, 2, 9, 20, 2>
            <<<dim3(B / 128, 21), 256, 0, stream>>>(y1, wuc2, buc2, wpc2, bpc2, wwl2, bwl2, y2, B);
        blockT_kernel<6, 16, 3, 2, 4, 9, 1>
            <<<dim3(B / 64, 4), 256, 0, stream>>>(y2, wuc3, buc3, wpc3, bpc3, wwl3, bwl3, y3, B);
        block4T_fc<<<B / 64, 256, 0, stream>>>(y3, wuc4, buc4, wpc4, bpc4, wwl4, bwl4,
                                               fcw, fcb, (float*)d_out, B);
    } else {
        // ---------------- fallback (round-1) ----------------
        float* y1 = ws;
        float* y2 = y1 + (size_t)B * 4 * 400;
        float* y3 = y2 + (size_t)B * 6 * 81;
        block_kernel<3, 4, 5, 3, 20, 64, 1>
            <<<B, 256, 0, stream>>>(x, wuc1, buc1, wpc1, bpc1, wwl1, bwl1, y1, B);
        block_kernel<4, 6, 3, 2, 9, 20, 4>
            <<<(B + 3) / 4, 256, 0, stream>>>(y1, wuc2, buc2, wpc2, bpc2, wwl2, bwl2, y2, B);
        block_kernel<6, 16, 3, 2, 4, 9, 16>
            <<<(B + 15) / 16, 256, 0, stream>>>(y2, wuc3, buc3, wpc3, bpc3, wwl3, bwl3, y3, B);
        block4_fc_kernel<<<(B + 7) / 8, 256, 0, stream>>>(
            y3, wuc4, buc4, wpc4, bpc4, wwl4, bwl4, fcw, fcb, (float*)d_out, B);
    }
}